// Round 7
// baseline (436.402 us; speedup 1.0000x reference)
//
#include <hip/hip_runtime.h>
#include <hip/hip_bf16.h>
#include <stdint.h>
#include <stddef.h>

#define B_ 4
#define N_ 1024
#define C_ 384
#define H_ 6
#define D_ 64
#define TC_ 1152          // 3*C
#define BHNN_ 25165824    // B*H*N*N
#define SCALE 0.125f
#define LOG2E 1.4426950408889634f
#define LN2 0.6931471805599453f

typedef __hip_bfloat16 bf16;
typedef __attribute__((ext_vector_type(2))) float f32x2;
typedef __attribute__((ext_vector_type(4))) float f32x4;
typedef __attribute__((ext_vector_type(8))) short short8;
typedef __attribute__((ext_vector_type(4))) short short4v;

union f4u { f32x4 v4; f32x2 v2[2]; };

__device__ __forceinline__ short f2bs(float x){
  bf16 b = __float2bfloat16(x);
  return *reinterpret_cast<short*>(&b);
}

// packed dual-FMA with src0 broadcast via op_sel (numerically = v_fma_f32 on both halves)
__device__ __forceinline__ void pk_fma_ll(f32x2& c, f32x2 a, f32x2 b){
  asm("v_pk_fma_f32 %0, %1, %2, %0 op_sel:[0,0,0] op_sel_hi:[0,1,1]" : "+v"(c) : "v"(a), "v"(b));
}
__device__ __forceinline__ void pk_fma_hh(f32x2& c, f32x2 a, f32x2 b){
  asm("v_pk_fma_f32 %0, %1, %2, %0 op_sel:[1,0,0] op_sel_hi:[1,1,1]" : "+v"(c) : "v"(a), "v"(b));
}

// ---------------- Threefry-2x32 (matches jax._src.prng) ----------------
#define TFR(x0,x1,r) { x0 += x1; x1 = ((x1)<<(r))|((x1)>>(32-(r))); x1 ^= x0; }

__host__ __device__ __forceinline__ void tf2x32(uint32_t k0, uint32_t k1,
                                                uint32_t& x0, uint32_t& x1){
  uint32_t k2 = k0 ^ k1 ^ 0x1BD11BDAu;
  x0 += k0; x1 += k1;
  TFR(x0,x1,13) TFR(x0,x1,15) TFR(x0,x1,26) TFR(x0,x1,6)
  x0 += k1; x1 += k2 + 1u;
  TFR(x0,x1,17) TFR(x0,x1,29) TFR(x0,x1,16) TFR(x0,x1,24)
  x0 += k2; x1 += k0 + 2u;
  TFR(x0,x1,13) TFR(x0,x1,15) TFR(x0,x1,26) TFR(x0,x1,6)
  x0 += k0; x1 += k1 + 3u;
  TFR(x0,x1,17) TFR(x0,x1,29) TFR(x0,x1,16) TFR(x0,x1,24)
  x0 += k1; x1 += k2 + 4u;
  TFR(x0,x1,13) TFR(x0,x1,15) TFR(x0,x1,26) TFR(x0,x1,6)
  x0 += k2; x1 += k0 + 5u;
}

__device__ __forceinline__ uint32_t rotl32(uint32_t x, uint32_t r){
#if __has_builtin(__builtin_amdgcn_alignbit)
  return __builtin_amdgcn_alignbit(x, x, 32u - r);
#else
  return (x << r) | (x >> (32u - r));
#endif
}

// dual-stream threefry: uniforms for BOTH gumbel keys at counter (0, j), 2-way ILP
__device__ __forceinline__ void tf_dual(uint32_t j,
    uint32_t ak0, uint32_t ak1, uint32_t ak2,
    uint32_t bk0, uint32_t bk1, uint32_t bk2,
    float& fA, float& fB){
  uint32_t x0 = ak0, x1 = j + ak1;
  uint32_t y0 = bk0, y1 = j + bk1;
  #define DTFR(r) { x0 += x1; y0 += y1;               \
                    x1 = rotl32(x1,(r)); y1 = rotl32(y1,(r)); \
                    x1 ^= x0; y1 ^= y0; }
  DTFR(13) DTFR(15) DTFR(26) DTFR(6)
  x0 += ak1; x1 += ak2 + 1u;  y0 += bk1; y1 += bk2 + 1u;
  DTFR(17) DTFR(29) DTFR(16) DTFR(24)
  x0 += ak2; x1 += ak0 + 2u;  y0 += bk2; y1 += bk0 + 2u;
  DTFR(13) DTFR(15) DTFR(26) DTFR(6)
  x0 += ak0; x1 += ak1 + 3u;  y0 += bk0; y1 += bk1 + 3u;
  DTFR(17) DTFR(29) DTFR(16) DTFR(24)
  x0 += ak1; x1 += ak2 + 4u;  y0 += bk1; y1 += bk2 + 4u;
  DTFR(13) DTFR(15) DTFR(26) DTFR(6)
  x0 += ak2; x1 += ak0 + 5u;  y0 += bk2; y1 += bk0 + 5u;
  #undef DTFR
  uint32_t bitsA = x0 ^ x1;
  uint32_t bitsB = y0 ^ y1;
  fA = fmaxf(__uint_as_float((bitsA >> 9) | 0x3F800000u) - 1.0f, 1.1754943508222875e-38f);
  fB = fmaxf(__uint_as_float((bitsB >> 9) | 0x3F800000u) - 1.0f, 1.1754943508222875e-38f);
}

// ---------------- Kernel P (prep): split x -> bf16 hi/lo; transpose+split qkv_w -> wT hi/lo
__global__ __launch_bounds__(256) void k_prep(const float* __restrict__ x,
                                              const float* __restrict__ w,
                                              short* __restrict__ xhi, short* __restrict__ xlo,
                                              short* __restrict__ wThi, short* __restrict__ wTlo){
  const int t = threadIdx.x;
  if (blockIdx.x < 432){
    const int kt = blockIdx.x % 12, nt = blockIdx.x / 12;
    __shared__ float T[32][33];
    const int col = t & 31, row8 = t >> 5;
    #pragma unroll
    for (int i = 0; i < 4; i++)
      T[row8 + i*8][col] = w[(size_t)(kt*32 + row8 + i*8)*TC_ + nt*32 + col];
    __syncthreads();
    #pragma unroll
    for (int i = 0; i < 4; i++){
      int n = nt*32 + row8 + i*8;
      int k = kt*32 + col;
      float v = T[col][row8 + i*8];          // = w[k][n]
      bf16 hb = __float2bfloat16(v);
      float hf = __bfloat162float(hb);
      bf16 lb = __float2bfloat16(v - hf);
      wThi[(size_t)n*C_ + k] = *(short*)&hb;
      wTlo[(size_t)n*C_ + k] = *(short*)&lb;
    }
  } else {
    const int b2 = blockIdx.x - 432;
    size_t base = ((size_t)b2*256 + t) * 4;
    #pragma unroll
    for (int it = 0; it < 8; it++){
      size_t idx = base + (size_t)it * 196608;    // 192*256*4
      f32x4 v = *(const f32x4*)&x[idx];
      short4v hs, ls;
      #pragma unroll
      for (int jj = 0; jj < 4; jj++){
        bf16 hb = __float2bfloat16(v[jj]);
        float hf = __bfloat162float(hb);
        bf16 lb = __float2bfloat16(v[jj] - hf);
        hs[jj] = *(short*)&hb; ls[jj] = *(short*)&lb;
      }
      *(short4v*)&xhi[idx] = hs;
      *(short4v*)&xlo[idx] = ls;
    }
  }
}

// ---------------- Kernel A (MFMA, bf16x2): qkv = x @ qkv_w + b
// R7: XCD-chunked swizzle (T1) — blocks ordered m-major, contiguous 144-block
// chunk per XCD, so each A-panel (98 KB) is read by exactly ONE XCD and stays
// L2-resident (8 panels x 98 KB = 784 KB << 4 MB XCD-L2). Was: every panel
// pulled by all 8 XCDs (~113 MB of L3 traffic).
__global__ __launch_bounds__(256) void k_qkv(const short* __restrict__ xhi,
                                             const short* __restrict__ xlo,
                                             const short* __restrict__ wThi,
                                             const short* __restrict__ wTlo,
                                             const float* __restrict__ bias,
                                             bf16* __restrict__ qb,
                                             bf16* __restrict__ kb,
                                             bf16* __restrict__ vTb){
  __shared__ __align__(16) short sA[2][64][32];   // [hi/lo][m][k]
  __shared__ __align__(16) short sB[2][64][32];   // [hi/lo][n][k]
  const int t = threadIdx.x, lane = t & 63, wv = t >> 6;
  const int lo = lane & 15, quad = lane >> 4;
  // bijective XCD chunking: 1152 = 8 * 144
  const int wg = (blockIdx.x & 7) * 144 + (blockIdx.x >> 3);
  const int m0 = (wg / 18) * 64, n0 = (wg % 18) * 64;
  const int sr = lane >> 2, skq = lane & 3;
  const short* srcAh = xhi  + (size_t)(m0 + wv*16 + sr)*C_ + skq*8;
  const short* srcAl = xlo  + (size_t)(m0 + wv*16 + sr)*C_ + skq*8;
  const short* srcBh = wThi + (size_t)(n0 + wv*16 + sr)*C_ + skq*8;
  const short* srcBl = wTlo + (size_t)(n0 + wv*16 + sr)*C_ + skq*8;
  short* dAh = &sA[0][wv*16 + sr][skq*8];   // byte off = wv*1024 + lane*16 (linear)
  short* dAl = &sA[1][wv*16 + sr][skq*8];
  short* dBh = &sB[0][wv*16 + sr][skq*8];
  short* dBl = &sB[1][wv*16 + sr][skq*8];

  f32x4 acc[4] = {{0,0,0,0},{0,0,0,0},{0,0,0,0},{0,0,0,0}};
  short8 ra = *(const short8*)(srcAh);
  short8 rb = *(const short8*)(srcAl);
  short8 rc = *(const short8*)(srcBh);
  short8 rd = *(const short8*)(srcBl);
  for (int k0 = 0; k0 < C_; k0 += 32){
    __syncthreads();                       // prev chunk's readers done
    *(short8*)dAh = ra; *(short8*)dAl = rb;
    *(short8*)dBh = rc; *(short8*)dBl = rd;
    if (k0 + 32 < C_){                     // prefetch next chunk (uniform branch)
      ra = *(const short8*)(srcAh + k0 + 32);
      rb = *(const short8*)(srcAl + k0 + 32);
      rc = *(const short8*)(srcBh + k0 + 32);
      rd = *(const short8*)(srcBl + k0 + 32);
    }
    __syncthreads();                       // staged data visible
    short8 ah = *(const short8*)&sA[0][wv*16 + lo][quad*8];
    short8 al = *(const short8*)&sA[1][wv*16 + lo][quad*8];
    #pragma unroll
    for (int j = 0; j < 4; j++){
      short8 bh = *(const short8*)&sB[0][j*16 + lo][quad*8];
      short8 bl = *(const short8*)&sB[1][j*16 + lo][quad*8];
      acc[j] = __builtin_amdgcn_mfma_f32_16x16x32_bf16(ah, bh, acc[j], 0, 0, 0);
      acc[j] = __builtin_amdgcn_mfma_f32_16x16x32_bf16(ah, bl, acc[j], 0, 0, 0);
      acc[j] = __builtin_amdgcn_mfma_f32_16x16x32_bf16(al, bh, acc[j], 0, 0, 0);
    }
  }
  #pragma unroll
  for (int j = 0; j < 4; j++){
    int ng = n0 + j*16 + lo;
    int t3 = ng / C_;
    int rem = ng - t3*C_;
    int hh = rem >> 6, dd = rem & 63;
    float bsv = bias[ng];
    #pragma unroll
    for (int r = 0; r < 4; r++){
      int mg = m0 + wv*16 + quad*4 + r;
      int bb = mg >> 10, nn = mg & 1023;
      bf16 val = __float2bfloat16(acc[j][r] + bsv);
      if (t3 == 0)      qb[((size_t)(bb*H_ + hh)*N_ + nn)*D_ + dd] = val;
      else if (t3 == 1) kb[((size_t)(bb*H_ + hh)*N_ + nn)*D_ + dd] = val;
      else              vTb[((size_t)(bb*H_ + hh)*D_ + dd)*N_ + nn] = val;
    }
  }
}

// ---------------- Kernel B (MFMA): scores[bh][n][m] = sum_d q[n,d]*k[m,d] -> f32 (attn region)
__global__ __launch_bounds__(256) void k_scores(const short* __restrict__ qb,
                                                const short* __restrict__ kb,
                                                float* __restrict__ qk){
  const int gw = blockIdx.x * 4 + (threadIdx.x >> 6);
  const int lane = threadIdx.x & 63;
  const int mt = gw & 63, nt = (gw >> 6) & 63, bh = gw >> 12;
  const int lo = lane & 15, quad = lane >> 4;
  const short* qrow = qb + ((size_t)bh*N_ + nt*16 + lo)*D_ + quad*8;
  const short* krow = kb + ((size_t)bh*N_ + mt*16 + lo)*D_ + quad*8;
  short8 a0 = *(const short8*)qrow;
  short8 b0 = *(const short8*)krow;
  short8 a1 = *(const short8*)(qrow + 32);
  short8 b1 = *(const short8*)(krow + 32);
  f32x4 acc = {0.f, 0.f, 0.f, 0.f};
  acc = __builtin_amdgcn_mfma_f32_16x16x32_bf16(a0, b0, acc, 0, 0, 0);
  acc = __builtin_amdgcn_mfma_f32_16x16x32_bf16(a1, b1, acc, 0, 0, 0);
  float* o = qk + (size_t)bh*N_*N_ + (size_t)(nt*16)*N_ + mt*16;
  #pragma unroll
  for (int r = 0; r < 4; r++)
    o[(size_t)(quad*4 + r)*N_ + lo] = acc[r];   // row=(lane>>4)*4+reg, col=lane&15
}

// ---------------- Kernel D (merged stats+softmax+conv+tanh+gumbel):
// R1 structure kept (131us, 90% VALUBusy). WRITE_AB variant additionally stores
// bf16(hard ? attn_mean : 0) — bit-identical to what k_av computed from f32+mbits
// (same exp*invS f32 product, same bf16 rounding). Values consumed immediately,
// no live-range extension (R2 lesson respected).
template<bool WRITE_AB>
__global__ __launch_bounds__(256) void k_fuse_t(float* __restrict__ attn,
                                              const float* __restrict__ cw,
                                              const float* __restrict__ cb,
                                              float* __restrict__ u_out,
                                              unsigned long long* __restrict__ mbits,
                                              bf16* __restrict__ ab,
                                              uint32_t g0k0, uint32_t g0k1,
                                              uint32_t g1k0, uint32_t g1k1){
  const int bn = blockIdx.x;                  // 0..4095
  const int bb = bn >> 10, n = bn & 1023;
  const int t = threadIdx.x, lane = t & 63, wid = t >> 6;
  __shared__ float redm[H_][4], reds[H_][4];

  float qv[H_][4];
  #pragma unroll
  for (int h = 0; h < H_; h++){
    const float* p = attn + (((size_t)(bb*H_ + h) << 10) + n) * N_;
    #pragma unroll
    for (int i = 0; i < 4; i++) qv[h][i] = p[t + 256*i];
  }
  #pragma unroll
  for (int h = 0; h < H_; h++){
    float mx = fmaxf(fmaxf(qv[h][0], qv[h][1]), fmaxf(qv[h][2], qv[h][3]));
    #pragma unroll
    for (int off = 32; off > 0; off >>= 1) mx = fmaxf(mx, __shfl_xor(mx, off));
    if (lane == 0) redm[h][wid] = mx;
  }
  __syncthreads();
  float mxh[H_];
  #pragma unroll
  for (int h = 0; h < H_; h++){
    mxh[h] = fmaxf(fmaxf(redm[h][0], redm[h][1]), fmaxf(redm[h][2], redm[h][3]));
    const float k2 = SCALE * LOG2E;
    float s = 0.f;
    #pragma unroll
    for (int i = 0; i < 4; i++) s += __builtin_amdgcn_exp2f((qv[h][i] - mxh[h]) * k2);
    #pragma unroll
    for (int off = 32; off > 0; off >>= 1) s += __shfl_xor(s, off);
    if (lane == 0) reds[h][wid] = s;
  }
  __syncthreads();
  float invS[H_];
  #pragma unroll
  for (int h = 0; h < H_; h++){
    float S = reds[h][0] + reds[h][1] + reds[h][2] + reds[h][3];
    invS[h] = __builtin_amdgcn_rcpf(S);
  }
  // write attn_mean (recompute exp)
  #pragma unroll
  for (int h = 0; h < H_; h++){
    float* p = attn + (((size_t)(bb*H_ + h) << 10) + n) * N_;
    const float k2 = SCALE * LOG2E;
    #pragma unroll
    for (int i = 0; i < 4; i++)
      p[t + 256*i] = __builtin_amdgcn_exp2f((qv[h][i] - mxh[h]) * k2) * invS[h];
  }
  // conv mix + u + gumbel hard bits
  const uint32_t a2k = g0k0 ^ g0k1 ^ 0x1BD11BDAu;
  const uint32_t b2k = g1k0 ^ g1k1 ^ 0x1BD11BDAu;
  const uint32_t jrow = ((uint32_t)(bb*H_) << 20) | ((uint32_t)n << 10);
  #pragma unroll
  for (int i = 0; i < 4; i++){
    const uint32_t m = (uint32_t)(t + 256*i);
    #pragma unroll
    for (int o = 0; o < H_; o++){
      float up = cb[o];
      #pragma unroll
      for (int h = 0; h < H_; h++) up += cw[o*H_ + h] * qv[h][i];
      float eneg = __builtin_amdgcn_exp2f(-2.0f * LOG2E * up);
      float uu   = __builtin_amdgcn_rcpf(1.0f + eneg);
      float tt   = 2.0f * uu - 1.0f;                      // tanh(up)
      float et   = __builtin_amdgcn_exp2f(tt * LOG2E);    // e^t
      uint32_t j = jrow + ((uint32_t)o << 20) + m;
      float f0, f1;
      tf_dual(j, g0k0, g0k1, a2k, g1k0, g1k1, b2k, f0, f1);
      float L0 = __builtin_amdgcn_logf(f0);               // log2(f0) <= 0
      float L1 = __builtin_amdgcn_logf(f1);
      int hard = L0 < L1 * et;
      u_out[(size_t)j] = uu;
      if (WRITE_AB){
        const float k2 = SCALE * LOG2E;
        float e = __builtin_amdgcn_exp2f((qv[o][i] - mxh[o]) * k2) * invS[o];
        bf16 mv = __float2bfloat16(hard ? e : 0.0f);
        ab[(size_t)j] = mv;
      } else {
        unsigned long long bal = __ballot(hard);
        if (lane == 0) mbits[(size_t)j >> 6] = bal;
      }
    }
  }
}

// ---------------- Kernel E (MFMA, mbits path): identical to R6 m-split version
__global__ __launch_bounds__(256) void k_av(const float* __restrict__ attn,
                                            const unsigned long long* __restrict__ mbits,
                                            const short* __restrict__ vTb,
                                            float* __restrict__ tmp){
  __shared__ __align__(16) float red[2][4][64][4];   // 8 KB
  const int w = threadIdx.x >> 6, lane = threadIdx.x & 63;
  const int ntl = w >> 1, mh = w & 1;
  const int bh = blockIdx.x >> 5, ntp = blockIdx.x & 31;
  const int nt = ntp*2 + ntl;
  const int bb = bh / H_, h = bh - bb*H_;
  const int lo = lane & 15, quad = lane >> 4;
  const int row = nt*16 + lo;
  const float* arow = attn + ((size_t)bh*N_ + row)*N_ + quad*8;
  const unsigned long long* mrow = mbits + (((size_t)bh*N_ + row)*N_ >> 6);
  const short* vbase = vTb + ((size_t)bh*D_ + lo)*N_ + quad*8;
  f32x4 acc[4] = {{0,0,0,0},{0,0,0,0},{0,0,0,0},{0,0,0,0}};
  const int mstart = mh * 512;
  for (int m0 = mstart; m0 < mstart + 512; m0 += 32){
    f32x4 av0 = *(const f32x4*)(arow + m0);
    f32x4 av1 = *(const f32x4*)(arow + m0 + 4);
    unsigned long long wb = mrow[(m0 + quad*8) >> 6];
    int base = (m0 + quad*8) & 63;
    float vals[8] = {av0[0], av0[1], av0[2], av0[3], av1[0], av1[1], av1[2], av1[3]};
    short8 a;
    #pragma unroll
    for (int j = 0; j < 8; j++)
      a[j] = f2bs(((wb >> (base + j)) & 1ull) ? vals[j] : 0.0f);
    #pragma unroll
    for (int dt = 0; dt < 4; dt++){
      short8 bv = *(const short8*)(vbase + (size_t)(dt*16)*N_ + m0);
      acc[dt] = __builtin_amdgcn_mfma_f32_16x16x32_bf16(a, bv, acc[dt], 0, 0, 0);
    }
  }
  if (mh == 1){
    #pragma unroll
    for (int dt = 0; dt < 4; dt++)
      *(f32x4*)&red[ntl][dt][lane][0] = acc[dt];
  }
  __syncthreads();
  if (mh == 0){
    float* o = tmp + ((size_t)(bb*N_) + nt*16)*C_ + h*D_;
    #pragma unroll
    for (int dt = 0; dt < 4; dt++){
      f32x4 other = *(const f32x4*)&red[ntl][dt][lane][0];
      f32x4 s = acc[dt] + other;
      #pragma unroll
      for (int r = 0; r < 4; r++)
        o[(size_t)(quad*4 + r)*C_ + dt*16 + lo] = s[r];
    }
  }
}

// ---------------- Kernel E2 (MFMA, ab path): a-frags loaded DIRECTLY as bf16 —
// no mbits, no f32 reads, no mask/cvt VALU. Read traffic halved (50 vs 100 MB).
__global__ __launch_bounds__(256) void k_av2(const short* __restrict__ ab,
                                             const short* __restrict__ vTb,
                                             float* __restrict__ tmp){
  __shared__ __align__(16) float red[2][4][64][4];   // 8 KB
  const int w = threadIdx.x >> 6, lane = threadIdx.x & 63;
  const int ntl = w >> 1, mh = w & 1;
  const int bh = blockIdx.x >> 5, ntp = blockIdx.x & 31;
  const int nt = ntp*2 + ntl;
  const int bb = bh / H_, h = bh - bb*H_;
  const int lo = lane & 15, quad = lane >> 4;
  const int row = nt*16 + lo;
  const short* abrow = ab + ((size_t)bh*N_ + row)*N_ + quad*8;
  const short* vbase = vTb + ((size_t)bh*D_ + lo)*N_ + quad*8;
  f32x4 acc[4] = {{0,0,0,0},{0,0,0,0},{0,0,0,0},{0,0,0,0}};
  const int mstart = mh * 512;
  for (int m0 = mstart; m0 < mstart + 512; m0 += 32){
    short8 a = *(const short8*)(abrow + m0);
    #pragma unroll
    for (int dt = 0; dt < 4; dt++){
      short8 bv = *(const short8*)(vbase + (size_t)(dt*16)*N_ + m0);
      acc[dt] = __builtin_amdgcn_mfma_f32_16x16x32_bf16(a, bv, acc[dt], 0, 0, 0);
    }
  }
  if (mh == 1){
    #pragma unroll
    for (int dt = 0; dt < 4; dt++)
      *(f32x4*)&red[ntl][dt][lane][0] = acc[dt];
  }
  __syncthreads();
  if (mh == 0){
    float* o = tmp + ((size_t)(bb*N_) + nt*16)*C_ + h*D_;
    #pragma unroll
    for (int dt = 0; dt < 4; dt++){
      f32x4 other = *(const f32x4*)&red[ntl][dt][lane][0];
      f32x4 s = acc[dt] + other;
      #pragma unroll
      for (int r = 0; r < 4; r++)
        o[(size_t)(quad*4 + r)*C_ + dt*16 + lo] = s[r];
    }
  }
}

// ---------------- Kernel F: out = tmp @ proj_w + proj_b, 32x64 tiles, packed FMA
// R7: XCD-chunked swizzle — 768 = 8*96 chunks, m-major: each XCD reads 16 tmp
// panels (784 KB) from its own L2 instead of all XCDs pulling all panels.
__global__ __launch_bounds__(256) void k_proj(const float* __restrict__ A,
                                              const float* __restrict__ w,
                                              const float* __restrict__ bias,
                                              float* __restrict__ out){
  __shared__ __align__(16) float As[16][36];
  __shared__ __align__(16) float Bs[16][68];
  const int t = threadIdx.x, tx = t & 15, ty = t >> 4;
  const int wg = ((int)blockIdx.x & 7) * 96 + ((int)blockIdx.x >> 3);  // 768 = 8*96
  const int m0 = (wg / 6) * 32, n0 = (wg % 6) * 64;
  const int am = t >> 3,        ak = (t & 7) * 2;
  const int bn = (t & 15) * 4,  bk = t >> 4;
  f32x2 c[2][2] = {};
  for (int k0 = 0; k0 < C_; k0 += 16){
    f32x2 av = *(const f32x2*)&A[(size_t)(m0+am)*C_ + k0 + ak];
    f32x4 bv = *(const f32x4*)&w[(size_t)(k0+bk)*C_ + n0 + bn];
    __syncthreads();
    As[ak+0][am] = av[0]; As[ak+1][am] = av[1];
    *(f32x4*)&Bs[bk][bn] = bv;
    __syncthreads();
    #pragma unroll
    for (int k = 0; k < 16; k++){
      f32x2 a2 = *(const f32x2*)&As[k][ty*2];
      f4u b; b.v4 = *(const f32x4*)&Bs[k][tx*4];
      pk_fma_ll(c[0][0], a2, b.v2[0]); pk_fma_ll(c[0][1], a2, b.v2[1]);
      pk_fma_hh(c[1][0], a2, b.v2[0]); pk_fma_hh(c[1][1], a2, b.v2[1]);
    }
  }
  #pragma unroll
  for (int i = 0; i < 2; i++)
    #pragma unroll
    for (int jp = 0; jp < 2; jp++)
      #pragma unroll
      for (int sub = 0; sub < 2; sub++){
        int jg = n0 + tx*4 + jp*2 + sub;
        out[(size_t)(m0+ty*2+i)*C_ + jg] = c[i][jp][sub] + bias[jg];
      }
}

extern "C" void kernel_launch(void* const* d_in, const int* in_sizes, int n_in,
                              void* d_out, int out_size, void* d_ws, size_t ws_size,
                              hipStream_t stream) {
  const float* x      = (const float*)d_in[0];
  const float* qkv_w  = (const float*)d_in[1];
  const float* qkv_b  = (const float*)d_in[2];
  const float* proj_w = (const float*)d_in[3];
  const float* proj_b = (const float*)d_in[4];
  const float* conv_w = (const float*)d_in[5];
  const float* conv_b = (const float*)d_in[6];

  float* out      = (float*)d_out;                      // B*N*C
  float* attn_out = out + (size_t)B_*N_*C_;             // B*H*N*N (scores then attn)
  float* u_out    = attn_out + (size_t)BHNN_;           // B*H*N*N

  // workspace layout (base 26.9 MB proven safe; ab-path +50.3 MB gated on ws_size)
  char* ws = (char*)d_ws;
  bf16*  qb    = (bf16*)ws;                             //  3,145,728 B
  bf16*  kb    = (bf16*)(ws + 3145728);                 //  3,145,728 B
  bf16*  vTb   = (bf16*)(ws + 6291456);                 //  3,145,728 B
  unsigned long long* mbits = (unsigned long long*)(ws + 9437184); // 3,145,728 B
  float* tmp   = (float*)(ws + 12582912);               //  6,291,456 B
  short* xhi   = (short*)(ws + 18874368);               //  3,145,728 B
  short* xlo   = (short*)(ws + 22020096);               //  3,145,728 B
  short* wThi  = (short*)(ws + 25165824);               //    884,736 B
  short* wTlo  = (short*)(ws + 26050560);               //    884,736 B  (end 26,935,296)
  bf16*  ab    = (bf16*)(ws + 26935296);                // 50,331,648 B (end 77,266,944)
  const bool big_ws = ws_size >= (size_t)77266944;

  uint32_t g0k0, g0k1, g1k0, g1k1;
  { uint32_t a = 0u, b = 0u; tf2x32(0u, 42u, a, b); g0k0 = a; g0k1 = b; }
  { uint32_t a = 0u, b = 1u; tf2x32(0u, 42u, a, b); g1k0 = a; g1k1 = b; }

  dim3 blk(256);
  k_prep  <<<dim3(624),     blk, 0, stream>>>(x, qkv_w, xhi, xlo, wThi, wTlo);
  k_qkv   <<<dim3(1152),    blk, 0, stream>>>(xhi, xlo, wThi, wTlo, qkv_b, qb, kb, vTb);
  k_scores<<<dim3(24576),   blk, 0, stream>>>((const short*)qb, (const short*)kb, attn_out);
  if (big_ws){
    k_fuse_t<true> <<<dim3(4096), blk, 0, stream>>>(attn_out, conv_w, conv_b,
                                                    u_out, mbits, ab,
                                                    g0k0, g0k1, g1k0, g1k1);
    k_av2 <<<dim3(768),     blk, 0, stream>>>((const short*)ab, (const short*)vTb, tmp);
  } else {
    k_fuse_t<false><<<dim3(4096), blk, 0, stream>>>(attn_out, conv_w, conv_b,
                                                    u_out, mbits, ab,
                                                    g0k0, g0k1, g1k0, g1k1);
    k_av  <<<dim3(768),     blk, 0, stream>>>(attn_out, mbits, (const short*)vTb, tmp);
  }
  k_proj  <<<dim3(768),     blk, 0, stream>>>(tmp, proj_w, proj_b, out);
}